// Round 1
// 248.782 us; speedup vs baseline: 1.0320x; 1.0320x over previous
//
#include <hip/hip_runtime.h>

// ZBL screened repulsion + sorted segment sum.
//   d_in[0] Z int32[500000], d_in[1] Dij fp32[16e6], d_in[2] idx_i int32[16e6] (sorted),
//   d_in[3] idx_j int32[16e6], d_in[4] p, d_in[5] d, d_in[6] c[4], d_in[7] a[4]
// Output: fp32[500000] segment_sum over idx_i.
//
// Established cost model (prior session rounds 2-9): divergent-gather cost
// ~4.6 cyc per active lane through the TCP miss-class path, invariant to
// occupancy, cache level, payload width, dedup, and masking. Structural
// floor for the gathers: 16M lanes x 4.6 / 256 CU / 2.4 GHz = 120us.
//
// This round:
//  (a) Stage kernel ELIMINATED. Only per-atom state needed is Z itself:
//      both Zi^p and Zj^p come from a 94-entry pow table built per-block
//      in LDS (95 powf/block, latency-hidden). j-side gathers Z[j] via the
//      same L2-direct (agent-scope sc0) path as the old zpf gather (same
//      per-lane cost, width-invariant); i-side gathers Z[i] plain (sorted
//      -> L1 hits, free). Launch = memset + edge kernel only.
//  (b) Wave-level segmented tail merge: idx_i sorted => per-wave tail keys
//      form contiguous non-decreasing runs; 6-step shfl_up run-scan merges
//      ~64 tail atomics/wave down to ~#distinct atoms (~32), removing
//      ~0.5M miss-class atomic lanes from the bottleneck VMEM pipe.

#define EPT   16        // edges per thread (16e6 divisible by 16)
#define BLOCK 256
#define MAXZ  95

__device__ __forceinline__ float fast_exp2(float x) {
#if __has_builtin(__builtin_amdgcn_exp2f)
    return __builtin_amdgcn_exp2f(x);   // v_exp_f32
#else
    return exp2f(x);
#endif
}

__global__ void __launch_bounds__(BLOCK) zbl_edge_kernel(
    const float* __restrict__ Dij,
    const int*   __restrict__ idx_i,
    const int*   __restrict__ idx_j,
    const int*   __restrict__ Z,
    const float* __restrict__ pptr,
    const float* __restrict__ dptr,
    const float* __restrict__ c,
    const float* __restrict__ a,
    float*       __restrict__ out,
    long long E)
{
    // Per-block pow table: pt[z] = z^p for z in [0,95). powf(0,p)=0 correct.
    // Cost: one powf latency on 1.5 waves per block, hidden behind the
    // other resident waves' gather traffic.
    __shared__ float pt[MAXZ];
    if (threadIdx.x < MAXZ) pt[threadIdx.x] = powf((float)threadIdx.x, pptr[0]);
    __syncthreads();

    const long long t    = (long long)blockIdx.x * BLOCK + threadIdx.x;
    const long long base = t * EPT;
    if (base >= E) return;

    const float LOG2E = 1.4426950408889634f;
    const float invd  = 1.0f / dptr[0];
    const float m0 = -a[0] * LOG2E * invd;
    const float m1 = -a[1] * LOG2E * invd;
    const float m2 = -a[2] * LOG2E * invd;
    const float m3 = -a[3] * LOG2E * invd;
    const float c0 = c[0], c1 = c[1], c2 = c[2], c3 = c[3];

    // A wave may use the shuffle-merge path only if all 64 lanes ran the
    // full-EPT path (true for every wave when EPT | E, except grid tail).
    const long long waveBase = (t & ~63LL) * EPT;
    const bool waveFull = (waveBase + 64LL * EPT) <= E;

    if (base + EPT <= E) {
        // Phase 1: coalesced streams into registers (12 x dwordx4, MLP).
        float dv[EPT];
        int   iv[EPT], jv[EPT];
#pragma unroll
        for (int v = 0; v < EPT; v += 4) {
            const float4 dq = *reinterpret_cast<const float4*>(Dij  + base + v);
            const int4   iq = *reinterpret_cast<const int4*>(idx_i + base + v);
            const int4   jq = *reinterpret_cast<const int4*>(idx_j + base + v);
            dv[v] = dq.x; dv[v+1] = dq.y; dv[v+2] = dq.z; dv[v+3] = dq.w;
            iv[v] = iq.x; iv[v+1] = iq.y; iv[v+2] = iq.z; iv[v+3] = iq.w;
            jv[v] = jq.x; jv[v+1] = jq.y; jv[v+2] = jq.z; jv[v+3] = jq.w;
        }
        // Phase 2a: j-gathers bypass L1 (agent scope => sc0 => L2 direct),
        // batched for MLP=16.
        int zj[EPT];
#pragma unroll
        for (int k = 0; k < EPT; ++k) {
            zj[k] = __hip_atomic_load(Z + jv[k], __ATOMIC_RELAXED,
                                      __HIP_MEMORY_SCOPE_AGENT);
        }
        // Phase 2b: i-gathers stay cached (sorted -> ~2 lines/wave, L1 hits).
        int zi[EPT];
#pragma unroll
        for (int k = 0; k < EPT; ++k) zi[k] = Z[iv[k]];

        // Phase 2c: resolve pow table in LDS for both sides (DS pipe,
        // parallel to the VMEM bottleneck).
        float zz[EPT];
#pragma unroll
        for (int k = 0; k < EPT; ++k) zz[k] = pt[zi[k]] + pt[zj[k]];

        // Phase 3: compute + segmented accumulate (idx_i sorted).
        int   cur = iv[0];
        float acc = 0.0f;
#pragma unroll
        for (int k = 0; k < EPT; ++k) {
            const float tt = dv[k] * zz[k];
            float v;
            v = c0 * fast_exp2(m0 * tt);
            v = fmaf(c1, fast_exp2(m1 * tt), v);
            v = fmaf(c2, fast_exp2(m2 * tt), v);
            v = fmaf(c3, fast_exp2(m3 * tt), v);
            if (iv[k] != cur) { atomicAdd(out + cur, acc); acc = 0.0f; cur = iv[k]; }
            acc += v;
        }

        if (waveFull) {
            // Wave-level run-segmented merge of the per-thread tails.
            // Tail keys are non-decreasing across lanes (idx_i sorted), so
            // equal keys form contiguous runs; conditional Hillis-Steele
            // scan leaves the run total in the last lane of each run.
            const int lane = threadIdx.x & 63;
            float vv  = acc;
            int   key = cur;
#pragma unroll
            for (int d2 = 1; d2 < 64; d2 <<= 1) {
                const float u  = __shfl_up(vv, d2, 64);
                const int   pk = __shfl_up(key, d2, 64);
                if (lane >= d2 && pk == key) vv += u;
            }
            const int nk = __shfl_down(key, 1, 64);
            if (lane == 63 || nk != key) atomicAdd(out + key, vv);
        } else {
            atomicAdd(out + cur, acc);
        }
    } else {
        // Grid-tail scalar path (never taken when EPT | E): direct atomics.
        int   cur = idx_i[base];
        float acc = 0.0f;
        for (long long e = base; e < E; ++e) {
            const int i  = idx_i[e];
            const int zj = __hip_atomic_load(Z + idx_j[e], __ATOMIC_RELAXED,
                                             __HIP_MEMORY_SCOPE_AGENT);
            const float tt = Dij[e] * (pt[Z[i]] + pt[zj]);
            float v;
            v = c0 * fast_exp2(m0 * tt);
            v = fmaf(c1, fast_exp2(m1 * tt), v);
            v = fmaf(c2, fast_exp2(m2 * tt), v);
            v = fmaf(c3, fast_exp2(m3 * tt), v);
            if (i != cur) { atomicAdd(out + cur, acc); acc = 0.0f; cur = i; }
            acc += v;
        }
        atomicAdd(out + cur, acc);
    }
}

extern "C" void kernel_launch(void* const* d_in, const int* in_sizes, int n_in,
                              void* d_out, int out_size, void* d_ws, size_t ws_size,
                              hipStream_t stream)
{
    const int*   Z     = (const int*)  d_in[0];
    const float* Dij   = (const float*)d_in[1];
    const int*   idx_i = (const int*)  d_in[2];
    const int*   idx_j = (const int*)  d_in[3];
    const float* p     = (const float*)d_in[4];
    const float* d     = (const float*)d_in[5];
    const float* c     = (const float*)d_in[6];
    const float* a     = (const float*)d_in[7];
    float*       out   = (float*)d_out;

    const long long E = in_sizes[1];

    // d_out is re-poisoned 0xAA before every timed launch; we need zeros.
    (void)hipMemsetAsync(d_out, 0, (size_t)out_size * sizeof(float), stream);

    const long long nThreads = (E + EPT - 1) / EPT;
    const int       nBlocks  = (int)((nThreads + BLOCK - 1) / BLOCK);
    zbl_edge_kernel<<<nBlocks, BLOCK, 0, stream>>>(
        Dij, idx_i, idx_j, Z, p, d, c, a, out, E);
}